// Round 3
// baseline (432.435 us; speedup 1.0000x reference)
//
#include <hip/hip_runtime.h>

#define NROW 8192
#define DIN  512
#define DOUT 256
#define NCHUNK 256
#define CLEN 32   // NCHUNK*CLEN == NROW

// ---------------- workspace layout (bytes) ----------------
constexpr size_t OFF_H      = 0;                              // 8192*256*4
constexpr size_t OFF_S1     = OFF_H + (size_t)NROW*DOUT*4;    // ---- memset region start
constexpr size_t OFF_S2     = OFF_S1 + NROW*4;
constexpr size_t OFF_RANK   = OFF_S2 + NROW*4;
constexpr size_t OFF_MISC   = OFF_RANK + NROW*4;              // [0]=enc-max u32, [1]=M1 float
constexpr size_t MEMSET_LEN = OFF_MISC + 256 - OFF_S1;        // s1,s2,rank,misc contiguous
constexpr size_t OFF_S1S    = OFF_MISC + 256;
constexpr size_t OFF_PERM   = OFF_S1S + NROW*4;
constexpr size_t OFF_WHI    = OFF_PERM + NROW*4;
constexpr size_t OFF_WLO    = OFF_WHI + NROW*4;
constexpr size_t OFF_PRELOS = OFF_WLO + NROW*4;               // 8193 floats, padded
constexpr size_t OFF_SUFHIS = OFF_PRELOS + 33024;
constexpr size_t OFF_CSLO   = OFF_SUFHIS + 33024;             // [NCHUNK] scalar chunk sums
constexpr size_t OFF_CSHI   = OFF_CSLO + 1024;
constexpr size_t OFF_TLO    = OFF_CSHI + 1024;                // [NCHUNK][256]
constexpr size_t OFF_THI    = OFF_TLO + (size_t)NCHUNK*DOUT*4;
constexpr size_t OFF_PRELO  = OFF_THI + (size_t)NCHUNK*DOUT*4;  // [8193][256]
constexpr size_t OFF_SUFHI  = OFF_PRELO + (size_t)(NROW+1)*DOUT*4;
// bf16 split copies of x and W (hi + lo parts)
constexpr size_t OFF_XHI    = OFF_SUFHI + (size_t)(NROW+1)*DOUT*4;
constexpr size_t OFF_XLO    = OFF_XHI + (size_t)NROW*DIN*2;
constexpr size_t OFF_BHI    = OFF_XLO + (size_t)NROW*DIN*2;
constexpr size_t OFF_BLO    = OFF_BHI + (size_t)DOUT*DIN*2;
constexpr size_t WS_NEED    = OFF_BLO + (size_t)DOUT*DIN*2;

typedef float f32x4 __attribute__((ext_vector_type(4)));
typedef short s16x8 __attribute__((ext_vector_type(8)));

__device__ __forceinline__ unsigned short bf16_rne(float f) {
  unsigned int u = __float_as_uint(f);
  return (unsigned short)((u + 0x7fffu + ((u >> 16) & 1u)) >> 16);
}

// ------- kernel 0: split x,W into bf16 hi/lo pairs (memory-bound, ~5us) ----
__global__ __launch_bounds__(256) void split_inputs(const float* __restrict__ x,
                                                    const float* __restrict__ W,
                                                    unsigned short* __restrict__ Xhi,
                                                    unsigned short* __restrict__ Xlo,
                                                    unsigned short* __restrict__ Bhi,
                                                    unsigned short* __restrict__ Blo) {
  const int b = blockIdx.x;
  const float* src;
  unsigned short *dh, *dl;
  size_t off;
  if (b < 2048) {
    off = ((size_t)b * 256 + threadIdx.x) * 8;
    src = x; dh = Xhi; dl = Xlo;
  } else {
    off = ((size_t)(b - 2048) * 256 + threadIdx.x) * 8;
    src = W; dh = Bhi; dl = Blo;
  }
  float4 u = *(const float4*)(src + off);
  float4 v = *(const float4*)(src + off + 4);
  float f[8] = {u.x, u.y, u.z, u.w, v.x, v.y, v.z, v.w};
  s16x8 hv, lv;
#pragma unroll
  for (int j = 0; j < 8; ++j) {
    unsigned short hh = bf16_rne(f[j]);
    float r = f[j] - __uint_as_float(((unsigned int)hh) << 16);
    hv[j] = (short)hh;
    lv[j] = (short)bf16_rne(r);
  }
  *(s16x8*)(dh + off) = hv;
  *(s16x8*)(dl + off) = lv;
}

// ------- kernel 1: h = x @ W^T via split-bf16 MFMA, fused s1/s2 ------------
// Tile 64x128, 256 thr = 4 waves (2x2), wave = 32x64 = 2x4 frags of
// v_mfma_f32_16x16x32_bf16 (verified layouts). LDS double-buffered (60 KB)
// -> ONE barrier per K-step; reg-prefetch has a full step to land (grid is
// 1 block/CU, so the dbuf IS the latency hiding). Frag-read ratio 12 reads /
// 24 MFMAs = 0.5 (was 0.67). Pitch 40 bf16 (80 B): balanced 8-lanes/bank-quad
// on b128 reads, 2-way (free) on writes.
__global__ __launch_bounds__(256) void gemm_h_mfma(const unsigned short* __restrict__ Xhi,
                                                   const unsigned short* __restrict__ Xlo,
                                                   const unsigned short* __restrict__ Bhi,
                                                   const unsigned short* __restrict__ Blo,
                                                   const float* __restrict__ a1,
                                                   const float* __restrict__ a2,
                                                   float* __restrict__ h,
                                                   float* __restrict__ s1,
                                                   float* __restrict__ s2) {
  __shared__ unsigned short AsH[2][64][40], AsL[2][64][40];
  __shared__ unsigned short BsH[2][128][40], BsL[2][128][40];
  const int tid = threadIdx.x;
  const int rowBase = blockIdx.x * 64;
  const int colBlk = blockIdx.y * 128;
  const int wid = tid >> 6, lane = tid & 63;
  const int wr = wid >> 1, wc = wid & 1;          // 2x2 wave grid: rows wr*32, cols wc*64
  const int lhi = lane >> 4, llo = lane & 15;

  f32x4 acc[2][4];
#pragma unroll
  for (int m = 0; m < 2; ++m)
#pragma unroll
    for (int n = 0; n < 4; ++n) acc[m][n] = (f32x4)(0.f);

  // staging: 384 row-slots (A:64 hi,64 lo; B:128 hi,128 lo) x 4 k-quarters,
  // 6 s16x8 per thread
  const int tr = tid >> 2, tq = tid & 3;
  const unsigned short* pAh = Xhi + (size_t)(rowBase + tr) * DIN + tq * 8;
  const unsigned short* pAl = Xlo + (size_t)(rowBase + tr) * DIN + tq * 8;
  const unsigned short* pBh0 = Bhi + (size_t)(colBlk + tr) * DIN + tq * 8;
  const unsigned short* pBh1 = Bhi + (size_t)(colBlk + 64 + tr) * DIN + tq * 8;
  const unsigned short* pBl0 = Blo + (size_t)(colBlk + tr) * DIN + tq * 8;
  const unsigned short* pBl1 = Blo + (size_t)(colBlk + 64 + tr) * DIN + tq * 8;

  s16x8 f0 = *(const s16x8*)pAh;
  s16x8 f1 = *(const s16x8*)pAl;
  s16x8 f2 = *(const s16x8*)pBh0;
  s16x8 f3 = *(const s16x8*)pBh1;
  s16x8 f4 = *(const s16x8*)pBl0;
  s16x8 f5 = *(const s16x8*)pBl1;

  int cur = 0;
  for (int k0 = 0; k0 < DIN; k0 += 32) {
    *(s16x8*)&AsH[cur][tr][tq * 8] = f0;
    *(s16x8*)&AsL[cur][tr][tq * 8] = f1;
    *(s16x8*)&BsH[cur][tr][tq * 8] = f2;
    *(s16x8*)&BsH[cur][64 + tr][tq * 8] = f3;
    *(s16x8*)&BsL[cur][tr][tq * 8] = f4;
    *(s16x8*)&BsL[cur][64 + tr][tq * 8] = f5;
    if (k0 + 32 < DIN) {  // prefetch next K-step: a full step to land
      f0 = *(const s16x8*)(pAh + k0 + 32);
      f1 = *(const s16x8*)(pAl + k0 + 32);
      f2 = *(const s16x8*)(pBh0 + k0 + 32);
      f3 = *(const s16x8*)(pBh1 + k0 + 32);
      f4 = *(const s16x8*)(pBl0 + k0 + 32);
      f5 = *(const s16x8*)(pBl1 + k0 + 32);
    }
    __syncthreads();  // buf[cur] staged; prev step's reads drained (lgkmcnt)
    s16x8 ah[2], al[2], bh[4], bl[4];
#pragma unroll
    for (int m = 0; m < 2; ++m) {
      ah[m] = *(const s16x8*)&AsH[cur][wr * 32 + m * 16 + llo][lhi * 8];
      al[m] = *(const s16x8*)&AsL[cur][wr * 32 + m * 16 + llo][lhi * 8];
    }
#pragma unroll
    for (int n = 0; n < 4; ++n) {
      bh[n] = *(const s16x8*)&BsH[cur][wc * 64 + n * 16 + llo][lhi * 8];
      bl[n] = *(const s16x8*)&BsL[cur][wc * 64 + n * 16 + llo][lhi * 8];
    }
#pragma unroll
    for (int m = 0; m < 2; ++m)
#pragma unroll
      for (int n = 0; n < 4; ++n) {
        acc[m][n] = __builtin_amdgcn_mfma_f32_16x16x32_bf16(ah[m], bh[n], acc[m][n], 0, 0, 0);
        acc[m][n] = __builtin_amdgcn_mfma_f32_16x16x32_bf16(al[m], bh[n], acc[m][n], 0, 0, 0);
        acc[m][n] = __builtin_amdgcn_mfma_f32_16x16x32_bf16(ah[m], bl[n], acc[m][n], 0, 0, 0);
      }
    cur ^= 1;
  }
  // C/D layout (m89-verified): col = lane&15, row = (lane>>4)*4 + reg
  float a1c[4], a2c[4];
#pragma unroll
  for (int n = 0; n < 4; ++n) {
    const int col = colBlk + wc * 64 + n * 16 + llo;
    a1c[n] = a1[col];
    a2c[n] = a2[col];
  }
#pragma unroll
  for (int m = 0; m < 2; ++m) {
    float p1[4] = {0.f, 0.f, 0.f, 0.f}, p2[4] = {0.f, 0.f, 0.f, 0.f};
#pragma unroll
    for (int n = 0; n < 4; ++n) {
      const int col = colBlk + wc * 64 + n * 16 + llo;
#pragma unroll
      for (int j = 0; j < 4; ++j) {
        const int row = rowBase + wr * 32 + m * 16 + lhi * 4 + j;
        h[(size_t)row * DOUT + col] = acc[m][n][j];
        p1[j] = fmaf(acc[m][n][j], a1c[n], p1[j]);
        p2[j] = fmaf(acc[m][n][j], a2c[n], p2[j]);
      }
    }
#pragma unroll
    for (int j = 0; j < 4; ++j) {
#pragma unroll
      for (int msk = 1; msk < 16; msk <<= 1) {
        p1[j] += __shfl_xor(p1[j], msk);
        p2[j] += __shfl_xor(p2[j], msk);
      }
    }
    if (llo == 0) {
#pragma unroll
      for (int j = 0; j < 4; ++j) {
        const int row = rowBase + wr * 32 + m * 16 + lhi * 4 + j;
        atomicAdd(&s1[row], p1[j]);
        atomicAdd(&s2[row], p2[j]);
      }
    }
  }
}

// ------- kernel 2: rank by counting (atomicAdd into rank) + global max -----
__global__ __launch_bounds__(256) void rank_count(const float* __restrict__ s1,
                                                  int* __restrict__ rank,
                                                  unsigned int* __restrict__ miscu) {
  __shared__ float sj[1024];
  __shared__ float wm[4];
  const int t = threadIdx.x;
  const int ib = blockIdx.x, jc = blockIdx.y;
  const int j0 = jc * 1024;
  *(float4*)&sj[t << 2] = *(const float4*)(s1 + j0 + (t << 2));
  const int i = ib * 256 + t;
  const float v = s1[i];
  __syncthreads();
  int cnt = 0;
#pragma unroll 4
  for (int q = 0; q < 256; ++q) {
    float4 sv = *(const float4*)&sj[q << 2];
    int jg = j0 + (q << 2);
    cnt += (int)(sv.x < v) + (int)((sv.x == v) & (jg + 0 < i));
    cnt += (int)(sv.y < v) + (int)((sv.y == v) & (jg + 1 < i));
    cnt += (int)(sv.z < v) + (int)((sv.z == v) & (jg + 2 < i));
    cnt += (int)(sv.w < v) + (int)((sv.w == v) & (jg + 3 < i));
  }
  atomicAdd(&rank[i], cnt);
  if (jc == 0) {  // one layer computes global max of s1 (monotone-uint atomicMax)
    float m = v;
#pragma unroll
    for (int off = 32; off > 0; off >>= 1) m = fmaxf(m, __shfl_down(m, off));
    if ((t & 63) == 0) wm[t >> 6] = m;
    __syncthreads();
    if (t == 0) {
      float mm = fmaxf(fmaxf(wm[0], wm[1]), fmaxf(wm[2], wm[3]));
      unsigned int b = __float_as_uint(mm);
      unsigned int enc = (b & 0x80000000u) ? ~b : (b | 0x80000000u);
      atomicMax(miscu, enc);
    }
  }
}

// ------- kernel 3: scatter into sorted order + exp weights -----------------
__global__ __launch_bounds__(256) void scatter_w(const float* __restrict__ s1,
                                                 const int* __restrict__ rank,
                                                 const unsigned int* __restrict__ miscu,
                                                 float* __restrict__ miscf,
                                                 float* __restrict__ s1s,
                                                 int* __restrict__ perm,
                                                 float* __restrict__ w_hi,
                                                 float* __restrict__ w_lo) {
  const int i = blockIdx.x * 256 + threadIdx.x;
  unsigned int e = miscu[0];
  unsigned int b = (e & 0x80000000u) ? (e & 0x7fffffffu) : ~e;
  const float M1 = __uint_as_float(b);
  const float v = s1[i];
  const int r = rank[i];
  s1s[r] = v;
  perm[r] = i;
  w_hi[r] = __expf(v - M1);
  w_lo[r] = __expf(0.2f * (v - M1));
  if (i == 0) miscf[0] = M1;
}

// ------- kernel 4: per-chunk weighted totals + scalar chunk sums -----------
__global__ __launch_bounds__(256) void chunk_totals(const float* __restrict__ h,
                                                    const int* __restrict__ perm,
                                                    const float* __restrict__ w_hi,
                                                    const float* __restrict__ w_lo,
                                                    float* __restrict__ T_lo,
                                                    float* __restrict__ T_hi,
                                                    float* __restrict__ cs_lo,
                                                    float* __restrict__ cs_hi) {
  const int d = threadIdx.x, b = blockIdx.x;
  const int j0 = b * CLEN;
  float tlo = 0.f, thi = 0.f;
#pragma unroll
  for (int e = 0; e < CLEN; e += 4) {
    int4 p4 = *(const int4*)(perm + j0 + e);
    float4 wl4 = *(const float4*)(w_lo + j0 + e);
    float4 wh4 = *(const float4*)(w_hi + j0 + e);
    float h0 = h[(size_t)p4.x * DOUT + d];
    float h1 = h[(size_t)p4.y * DOUT + d];
    float h2 = h[(size_t)p4.z * DOUT + d];
    float h3 = h[(size_t)p4.w * DOUT + d];
    tlo += wl4.x * h0 + wl4.y * h1 + wl4.z * h2 + wl4.w * h3;
    thi += wh4.x * h0 + wh4.y * h1 + wh4.z * h2 + wh4.w * h3;
  }
  T_lo[b * DOUT + d] = tlo;
  T_hi[b * DOUT + d] = thi;
  if (d < 64) {  // wave 0: scalar sums of this chunk's weights
    float wl = (d < 32) ? w_lo[j0 + d] : 0.f;
    float wh = (d < 32) ? w_hi[j0 + d] : 0.f;
#pragma unroll
    for (int off = 32; off > 0; off >>= 1) {
      wl += __shfl_down(wl, off);
      wh += __shfl_down(wh, off);
    }
    if (d == 0) { cs_lo[b] = wl; cs_hi[b] = wh; }
  }
}

// ------- kernel 5: chunk-offset sums + materialize PreLo/SufHi + scalars ---
// De-spilled: cache the 64 weight*h PRODUCTS (not 96 raw values); T-loops
// run exact ranges (avg 255 loads instead of 512).
__global__ __launch_bounds__(256) void write_prefix(const float* __restrict__ h,
                                                    const int* __restrict__ perm,
                                                    const float* __restrict__ w_hi,
                                                    const float* __restrict__ w_lo,
                                                    const float* __restrict__ T_lo,
                                                    const float* __restrict__ T_hi,
                                                    const float* __restrict__ cs_lo,
                                                    const float* __restrict__ cs_hi,
                                                    float* __restrict__ PreLo,
                                                    float* __restrict__ SufHi,
                                                    float* __restrict__ prelo_s,
                                                    float* __restrict__ sufhi_s) {
  const int d = threadIdx.x, b = blockIdx.x;
  const int j0 = b * CLEN;
  // wave 0 additionally computes the scalar denominator prefixes
  if (d < 64) {
    float accp = 0.f, acct = 0.f;
    for (int p = d; p < NCHUNK; p += 64) {
      float cl = cs_lo[p], ch = cs_hi[p];
      accp += (p < b) ? cl : 0.f;
      acct += (p > b) ? ch : 0.f;
    }
#pragma unroll
    for (int off = 32; off > 0; off >>= 1) {
      accp += __shfl_down(accp, off);
      acct += __shfl_down(acct, off);
    }
    float pres  = __shfl(accp, 0);
    float tails = __shfl(acct, 0);
    float wl = (d < 32) ? w_lo[j0 + d] : 0.f;
    float wh = (d < 32) ? w_hi[j0 + d] : 0.f;
    float pl = wl, ph = wh;  // inclusive prefix over 32 lanes
#pragma unroll
    for (int off = 1; off < 32; off <<= 1) {
      float a = __shfl_up(pl, off);
      float c = __shfl_up(ph, off);
      if (d >= off) { pl += a; ph += c; }
    }
    float chunk_hi_tot = __shfl(ph, 31);
    if (d < 32) {
      prelo_s[j0 + d] = pres + (pl - wl);
      sufhi_s[j0 + d] = tails + (chunk_hi_tot - (ph - wh));
    }
    if (b == NCHUNK - 1 && d == 31) {
      prelo_s[NROW] = pres + pl;
      sufhi_s[NROW] = 0.f;
    }
  }
  float rl = 0.f, tail = 0.f;
  for (int p = 0; p < b; ++p)           rl   += T_lo[p * DOUT + d];
  for (int p = b + 1; p < NCHUNK; ++p)  tail += T_hi[p * DOUT + d];
  float phl[CLEN], phh[CLEN];
  float ownHi = 0.f;
#pragma unroll
  for (int e = 0; e < CLEN; e += 4) {
    int4 p4 = *(const int4*)(perm + j0 + e);
    float4 wl4 = *(const float4*)(w_lo + j0 + e);
    float4 wh4 = *(const float4*)(w_hi + j0 + e);
    float h0 = h[(size_t)p4.x * DOUT + d];
    float h1 = h[(size_t)p4.y * DOUT + d];
    float h2 = h[(size_t)p4.z * DOUT + d];
    float h3 = h[(size_t)p4.w * DOUT + d];
    phl[e + 0] = wl4.x * h0; phl[e + 1] = wl4.y * h1;
    phl[e + 2] = wl4.z * h2; phl[e + 3] = wl4.w * h3;
    phh[e + 0] = wh4.x * h0; phh[e + 1] = wh4.y * h1;
    phh[e + 2] = wh4.z * h2; phh[e + 3] = wh4.w * h3;
    ownHi += phh[e + 0] + phh[e + 1] + phh[e + 2] + phh[e + 3];
  }
  float shb = tail + ownHi;
  float preh = 0.f;
#pragma unroll
  for (int e = 0; e < CLEN; ++e) {
    size_t j = (size_t)(j0 + e);
    PreLo[j * DOUT + d] = rl;
    SufHi[j * DOUT + d] = shb - preh;
    rl   += phl[e];
    preh += phh[e];
  }
  if (b == NCHUNK - 1) {
    PreLo[(size_t)NROW * DOUT + d] = rl;
    SufHi[(size_t)NROW * DOUT + d] = 0.f;
  }
}

// ---------------- kernel 6: per-row combine -------------------------------
__global__ __launch_bounds__(256) void finalize(const float* __restrict__ s2,
                                                const float* __restrict__ s1s,
                                                const float* __restrict__ miscf,
                                                const float* __restrict__ PreLo,
                                                const float* __restrict__ SufHi,
                                                const float* __restrict__ prelo_s,
                                                const float* __restrict__ sufhi_s,
                                                float* __restrict__ out) {
  const int wave = threadIdx.x >> 6, lane = threadIdx.x & 63;
  const int i = blockIdx.x * 4 + wave;
  const float c = s2[i];
  const float M1 = miscf[0];
  const float tval = -c;
  int lo = 0, hi = NROW;
  while (lo < hi) {
    int mid = (lo + hi) >> 1;
    if (s1s[mid] <= tval) lo = mid + 1; else hi = mid;
  }
  const int k = lo;
  const float u = c + M1;
  const float m = fmaxf(u, 0.2f * u);
  const float fh = __expf(u - m);
  const float fl = __expf(0.2f * u - m);
  const float den = fh * sufhi_s[k] + fl * prelo_s[k];
  const float inv = 1.f / den;
  float4 A = *(const float4*)(SufHi + (size_t)k * DOUT + (lane << 2));
  float4 B = *(const float4*)(PreLo + (size_t)k * DOUT + (lane << 2));
  float4 o;
  o.x = (fh * A.x + fl * B.x) * inv;
  o.y = (fh * A.y + fl * B.y) * inv;
  o.z = (fh * A.z + fl * B.z) * inv;
  o.w = (fh * A.w + fl * B.w) * inv;
  *(float4*)(out + (size_t)i * DOUT + (lane << 2)) = o;
}

extern "C" void kernel_launch(void* const* d_in, const int* in_sizes, int n_in,
                              void* d_out, int out_size, void* d_ws, size_t ws_size,
                              hipStream_t stream) {
  const float* x  = (const float*)d_in[0];
  const float* W  = (const float*)d_in[2];
  const float* a1 = (const float*)d_in[3];
  const float* a2 = (const float*)d_in[4];
  float* out = (float*)d_out;

  char* ws = (char*)d_ws;
  if (ws_size < WS_NEED) ws = (char*)d_in[1];  // fall back to unused adj buffer

  float*          h       = (float*)(ws + OFF_H);
  float*          s1      = (float*)(ws + OFF_S1);
  float*          s2      = (float*)(ws + OFF_S2);
  int*            rank    = (int*)  (ws + OFF_RANK);
  unsigned int*   miscu   = (unsigned int*)(ws + OFF_MISC);
  float*          miscf   = (float*)(ws + OFF_MISC) + 1;
  float*          s1s     = (float*)(ws + OFF_S1S);
  int*            perm    = (int*)  (ws + OFF_PERM);
  float*          w_hi    = (float*)(ws + OFF_WHI);
  float*          w_lo    = (float*)(ws + OFF_WLO);
  float*          prelo_s = (float*)(ws + OFF_PRELOS);
  float*          sufhi_s = (float*)(ws + OFF_SUFHIS);
  float*          cs_lo   = (float*)(ws + OFF_CSLO);
  float*          cs_hi   = (float*)(ws + OFF_CSHI);
  float*          T_lo    = (float*)(ws + OFF_TLO);
  float*          T_hi    = (float*)(ws + OFF_THI);
  float*          PreLo   = (float*)(ws + OFF_PRELO);
  float*          SufHi   = (float*)(ws + OFF_SUFHI);
  unsigned short* Xhi     = (unsigned short*)(ws + OFF_XHI);
  unsigned short* Xlo     = (unsigned short*)(ws + OFF_XLO);
  unsigned short* Bhi     = (unsigned short*)(ws + OFF_BHI);
  unsigned short* Blo     = (unsigned short*)(ws + OFF_BLO);

  // zero s1,s2,rank,misc (contiguous) for the atomic accumulations
  hipMemsetAsync(s1, 0, MEMSET_LEN, stream);

  split_inputs<<<2048 + 64, 256, 0, stream>>>(x, W, Xhi, Xlo, Bhi, Blo);
  gemm_h_mfma<<<dim3(NROW / 64, DOUT / 128), 256, 0, stream>>>(Xhi, Xlo, Bhi, Blo,
                                                               a1, a2, h, s1, s2);
  rank_count<<<dim3(NROW / 256, 8), 256, 0, stream>>>(s1, rank, miscu);
  scatter_w<<<NROW / 256, 256, 0, stream>>>(s1, rank, miscu, miscf, s1s, perm, w_hi, w_lo);
  chunk_totals<<<NCHUNK, 256, 0, stream>>>(h, perm, w_hi, w_lo, T_lo, T_hi, cs_lo, cs_hi);
  write_prefix<<<NCHUNK, 256, 0, stream>>>(h, perm, w_hi, w_lo, T_lo, T_hi, cs_lo, cs_hi,
                                           PreLo, SufHi, prelo_s, sufhi_s);
  finalize<<<NROW / 4, 256, 0, stream>>>(s2, s1s, miscf, PreLo, SufHi, prelo_s, sufhi_s, out);
}

// Round 4
// 387.925 us; speedup vs baseline: 1.1147x; 1.1147x over previous
//
#include <hip/hip_runtime.h>

#define NROW 8192
#define DIN  512
#define DOUT 256
#define NCHUNK 256
#define CLEN 32   // NCHUNK*CLEN == NROW

// ---------------- workspace layout (bytes) ----------------
constexpr size_t OFF_H      = 0;                              // 8192*256*4
constexpr size_t OFF_S1     = OFF_H + (size_t)NROW*DOUT*4;    // ---- memset region start
constexpr size_t OFF_S2     = OFF_S1 + NROW*4;
constexpr size_t OFF_RANK   = OFF_S2 + NROW*4;
constexpr size_t OFF_MISC   = OFF_RANK + NROW*4;              // [0]=enc-max u32, [1]=M1 float
constexpr size_t MEMSET_LEN = OFF_MISC + 256 - OFF_S1;        // s1,s2,rank,misc contiguous
constexpr size_t OFF_S1S    = OFF_MISC + 256;
constexpr size_t OFF_PERM   = OFF_S1S + NROW*4;
constexpr size_t OFF_WHI    = OFF_PERM + NROW*4;
constexpr size_t OFF_WLO    = OFF_WHI + NROW*4;
constexpr size_t OFF_PRELOS = OFF_WLO + NROW*4;               // 8193 floats, padded
constexpr size_t OFF_SUFHIS = OFF_PRELOS + 33024;
constexpr size_t OFF_CSLO   = OFF_SUFHIS + 33024;             // [NCHUNK] scalar chunk sums
constexpr size_t OFF_CSHI   = OFF_CSLO + 1024;
constexpr size_t OFF_TLO    = OFF_CSHI + 1024;                // [NCHUNK][256]
constexpr size_t OFF_THI    = OFF_TLO + (size_t)NCHUNK*DOUT*4;
constexpr size_t OFF_PRELO  = OFF_THI + (size_t)NCHUNK*DOUT*4;  // [8193][256]
constexpr size_t OFF_SUFHI  = OFF_PRELO + (size_t)(NROW+1)*DOUT*4;
// bf16 split copies of x and W (hi + lo parts)
constexpr size_t OFF_XHI    = OFF_SUFHI + (size_t)(NROW+1)*DOUT*4;
constexpr size_t OFF_XLO    = OFF_XHI + (size_t)NROW*DIN*2;
constexpr size_t OFF_BHI    = OFF_XLO + (size_t)NROW*DIN*2;
constexpr size_t OFF_BLO    = OFF_BHI + (size_t)DOUT*DIN*2;
constexpr size_t WS_NEED    = OFF_BLO + (size_t)DOUT*DIN*2;

typedef float f32x4 __attribute__((ext_vector_type(4)));
typedef short s16x8 __attribute__((ext_vector_type(8)));

__device__ __forceinline__ unsigned short bf16_rne(float f) {
  unsigned int u = __float_as_uint(f);
  return (unsigned short)((u + 0x7fffu + ((u >> 16) & 1u)) >> 16);
}

// ------- kernel 0: split x,W into bf16 hi/lo pairs (memory-bound, ~5us) ----
__global__ __launch_bounds__(256) void split_inputs(const float* __restrict__ x,
                                                    const float* __restrict__ W,
                                                    unsigned short* __restrict__ Xhi,
                                                    unsigned short* __restrict__ Xlo,
                                                    unsigned short* __restrict__ Bhi,
                                                    unsigned short* __restrict__ Blo) {
  const int b = blockIdx.x;
  const float* src;
  unsigned short *dh, *dl;
  size_t off;
  if (b < 2048) {
    off = ((size_t)b * 256 + threadIdx.x) * 8;
    src = x; dh = Xhi; dl = Xlo;
  } else {
    off = ((size_t)(b - 2048) * 256 + threadIdx.x) * 8;
    src = W; dh = Bhi; dl = Blo;
  }
  float4 u = *(const float4*)(src + off);
  float4 v = *(const float4*)(src + off + 4);
  float f[8] = {u.x, u.y, u.z, u.w, v.x, v.y, v.z, v.w};
  s16x8 hv, lv;
#pragma unroll
  for (int j = 0; j < 8; ++j) {
    unsigned short hh = bf16_rne(f[j]);
    float r = f[j] - __uint_as_float(((unsigned int)hh) << 16);
    hv[j] = (short)hh;
    lv[j] = (short)bf16_rne(r);
  }
  *(s16x8*)(dh + off) = hv;
  *(s16x8*)(dl + off) = lv;
}

// ------- kernel 1: h = x @ W^T via split-bf16 MFMA, fused s1/s2 ------------
// ROUND-2 STRUCTURE (known-good): 64x64 tile, 20 KB single-buffered LDS,
// 512 blocks = 2 blocks/CU (occupancy is the latency hiding — round 3's
// 1-block/CU dbuf variant regressed 51us). NEW: XCD-chunked bid swizzle so
// the 4 col-tiles sharing an A-panel (128 KB) are contiguous on one XCD;
// 16 panels x 128 KB = 2 MB < 4 MB L2 -> A HBM traffic ~64 -> ~16 MB.
__global__ __launch_bounds__(256) void gemm_h_mfma(const unsigned short* __restrict__ Xhi,
                                                   const unsigned short* __restrict__ Xlo,
                                                   const unsigned short* __restrict__ Bhi,
                                                   const unsigned short* __restrict__ Blo,
                                                   const float* __restrict__ a1,
                                                   const float* __restrict__ a2,
                                                   float* __restrict__ h,
                                                   float* __restrict__ s1,
                                                   float* __restrict__ s2) {
  __shared__ unsigned short AsH[64][40], AsL[64][40], BsH[64][40], BsL[64][40];
  const int tid = threadIdx.x;
  // bijective XCD swizzle: nwg=512, 8 XCDs, 64 blocks/XCD-chunk
  const int bid = blockIdx.x;
  const int swz = (bid & 7) * 64 + (bid >> 3);
  const int rowBase = (swz >> 2) * 64;   // 128 row tiles
  const int colBase = (swz & 3) * 64;    // 4 col tiles (same A-panel adjacent)
  const int wid = tid >> 6, lane = tid & 63;
  const int wRow = wid >> 1, wCol = wid & 1;      // 2x2 wave grid
  const int lhi = lane >> 4, llo = lane & 15;

  f32x4 acc[2][2];
#pragma unroll
  for (int m = 0; m < 2; ++m)
#pragma unroll
    for (int n = 0; n < 2; ++n) acc[m][n] = (f32x4)(0.f);

  const int sr = tid >> 2;   // staging row 0..63
  const int sq = tid & 3;    // k-quarter (8 bf16 each)
  const unsigned short* xh = Xhi + (size_t)(rowBase + sr) * DIN + sq * 8;
  const unsigned short* xl = Xlo + (size_t)(rowBase + sr) * DIN + sq * 8;
  const unsigned short* bh = Bhi + (size_t)(colBase + sr) * DIN + sq * 8;
  const unsigned short* bl = Blo + (size_t)(colBase + sr) * DIN + sq * 8;

  s16x8 rah = *(const s16x8*)(xh);
  s16x8 ral = *(const s16x8*)(xl);
  s16x8 rbh = *(const s16x8*)(bh);
  s16x8 rbl = *(const s16x8*)(bl);

  for (int k0 = 0; k0 < DIN; k0 += 32) {
    __syncthreads();  // previous step's frag reads complete
    *(s16x8*)&AsH[sr][sq * 8] = rah;
    *(s16x8*)&AsL[sr][sq * 8] = ral;
    *(s16x8*)&BsH[sr][sq * 8] = rbh;
    *(s16x8*)&BsL[sr][sq * 8] = rbl;
    __syncthreads();  // staged tile visible
    if (k0 + 32 < DIN) {  // prefetch next K-step (latency hides under MFMAs)
      rah = *(const s16x8*)(xh + k0 + 32);
      ral = *(const s16x8*)(xl + k0 + 32);
      rbh = *(const s16x8*)(bh + k0 + 32);
      rbl = *(const s16x8*)(bl + k0 + 32);
    }
    s16x8 afh[2], afl[2], bfh[2], bfl[2];
#pragma unroll
    for (int m = 0; m < 2; ++m) {
      afh[m] = *(const s16x8*)&AsH[wRow * 32 + m * 16 + llo][lhi * 8];
      afl[m] = *(const s16x8*)&AsL[wRow * 32 + m * 16 + llo][lhi * 8];
    }
#pragma unroll
    for (int n = 0; n < 2; ++n) {
      bfh[n] = *(const s16x8*)&BsH[wCol * 32 + n * 16 + llo][lhi * 8];
      bfl[n] = *(const s16x8*)&BsL[wCol * 32 + n * 16 + llo][lhi * 8];
    }
#pragma unroll
    for (int m = 0; m < 2; ++m)
#pragma unroll
      for (int n = 0; n < 2; ++n) {
        acc[m][n] = __builtin_amdgcn_mfma_f32_16x16x32_bf16(afh[m], bfh[n], acc[m][n], 0, 0, 0);
        acc[m][n] = __builtin_amdgcn_mfma_f32_16x16x32_bf16(afl[m], bfh[n], acc[m][n], 0, 0, 0);
        acc[m][n] = __builtin_amdgcn_mfma_f32_16x16x32_bf16(afh[m], bfl[n], acc[m][n], 0, 0, 0);
      }
  }
  // C/D layout (m89-verified): col = lane&15, row = (lane>>4)*4 + reg
  float a1c[2], a2c[2];
#pragma unroll
  for (int n = 0; n < 2; ++n) {
    const int col = colBase + wCol * 32 + n * 16 + llo;
    a1c[n] = a1[col];
    a2c[n] = a2[col];
  }
#pragma unroll
  for (int m = 0; m < 2; ++m) {
    float p1[4] = {0.f, 0.f, 0.f, 0.f}, p2[4] = {0.f, 0.f, 0.f, 0.f};
#pragma unroll
    for (int n = 0; n < 2; ++n) {
      const int col = colBase + wCol * 32 + n * 16 + llo;
#pragma unroll
      for (int j = 0; j < 4; ++j) {
        const int row = rowBase + wRow * 32 + m * 16 + lhi * 4 + j;
        h[(size_t)row * DOUT + col] = acc[m][n][j];
        p1[j] = fmaf(acc[m][n][j], a1c[n], p1[j]);
        p2[j] = fmaf(acc[m][n][j], a2c[n], p2[j]);
      }
    }
#pragma unroll
    for (int j = 0; j < 4; ++j) {
#pragma unroll
      for (int msk = 1; msk < 16; msk <<= 1) {
        p1[j] += __shfl_xor(p1[j], msk);
        p2[j] += __shfl_xor(p2[j], msk);
      }
    }
    if (llo == 0) {
#pragma unroll
      for (int j = 0; j < 4; ++j) {
        const int row = rowBase + wRow * 32 + m * 16 + lhi * 4 + j;
        atomicAdd(&s1[row], p1[j]);
        atomicAdd(&s2[row], p2[j]);
      }
    }
  }
}

// ------- kernel 2: rank by counting (atomicAdd into rank) + global max -----
__global__ __launch_bounds__(256) void rank_count(const float* __restrict__ s1,
                                                  int* __restrict__ rank,
                                                  unsigned int* __restrict__ miscu) {
  __shared__ float sj[1024];
  __shared__ float wm[4];
  const int t = threadIdx.x;
  const int ib = blockIdx.x, jc = blockIdx.y;
  const int j0 = jc * 1024;
  *(float4*)&sj[t << 2] = *(const float4*)(s1 + j0 + (t << 2));
  const int i = ib * 256 + t;
  const float v = s1[i];
  __syncthreads();
  int cnt = 0;
#pragma unroll 4
  for (int q = 0; q < 256; ++q) {
    float4 sv = *(const float4*)&sj[q << 2];
    int jg = j0 + (q << 2);
    cnt += (int)(sv.x < v) + (int)((sv.x == v) & (jg + 0 < i));
    cnt += (int)(sv.y < v) + (int)((sv.y == v) & (jg + 1 < i));
    cnt += (int)(sv.z < v) + (int)((sv.z == v) & (jg + 2 < i));
    cnt += (int)(sv.w < v) + (int)((sv.w == v) & (jg + 3 < i));
  }
  atomicAdd(&rank[i], cnt);
  if (jc == 0) {  // one layer computes global max of s1 (monotone-uint atomicMax)
    float m = v;
#pragma unroll
    for (int off = 32; off > 0; off >>= 1) m = fmaxf(m, __shfl_down(m, off));
    if ((t & 63) == 0) wm[t >> 6] = m;
    __syncthreads();
    if (t == 0) {
      float mm = fmaxf(fmaxf(wm[0], wm[1]), fmaxf(wm[2], wm[3]));
      unsigned int b = __float_as_uint(mm);
      unsigned int enc = (b & 0x80000000u) ? ~b : (b | 0x80000000u);
      atomicMax(miscu, enc);
    }
  }
}

// ------- kernel 3: scatter into sorted order + exp weights -----------------
__global__ __launch_bounds__(256) void scatter_w(const float* __restrict__ s1,
                                                 const int* __restrict__ rank,
                                                 const unsigned int* __restrict__ miscu,
                                                 float* __restrict__ miscf,
                                                 float* __restrict__ s1s,
                                                 int* __restrict__ perm,
                                                 float* __restrict__ w_hi,
                                                 float* __restrict__ w_lo) {
  const int i = blockIdx.x * 256 + threadIdx.x;
  unsigned int e = miscu[0];
  unsigned int b = (e & 0x80000000u) ? (e & 0x7fffffffu) : ~e;
  const float M1 = __uint_as_float(b);
  const float v = s1[i];
  const int r = rank[i];
  s1s[r] = v;
  perm[r] = i;
  w_hi[r] = __expf(v - M1);
  w_lo[r] = __expf(0.2f * (v - M1));
  if (i == 0) miscf[0] = M1;
}

// ------- kernel 4: per-chunk weighted totals + scalar chunk sums -----------
__global__ __launch_bounds__(256) void chunk_totals(const float* __restrict__ h,
                                                    const int* __restrict__ perm,
                                                    const float* __restrict__ w_hi,
                                                    const float* __restrict__ w_lo,
                                                    float* __restrict__ T_lo,
                                                    float* __restrict__ T_hi,
                                                    float* __restrict__ cs_lo,
                                                    float* __restrict__ cs_hi) {
  const int d = threadIdx.x, b = blockIdx.x;
  const int j0 = b * CLEN;
  float tlo = 0.f, thi = 0.f;
#pragma unroll
  for (int e = 0; e < CLEN; e += 4) {
    int4 p4 = *(const int4*)(perm + j0 + e);
    float4 wl4 = *(const float4*)(w_lo + j0 + e);
    float4 wh4 = *(const float4*)(w_hi + j0 + e);
    float h0 = h[(size_t)p4.x * DOUT + d];
    float h1 = h[(size_t)p4.y * DOUT + d];
    float h2 = h[(size_t)p4.z * DOUT + d];
    float h3 = h[(size_t)p4.w * DOUT + d];
    tlo += wl4.x * h0 + wl4.y * h1 + wl4.z * h2 + wl4.w * h3;
    thi += wh4.x * h0 + wh4.y * h1 + wh4.z * h2 + wh4.w * h3;
  }
  T_lo[b * DOUT + d] = tlo;
  T_hi[b * DOUT + d] = thi;
  if (d < 64) {  // wave 0: scalar sums of this chunk's weights
    float wl = (d < 32) ? w_lo[j0 + d] : 0.f;
    float wh = (d < 32) ? w_hi[j0 + d] : 0.f;
#pragma unroll
    for (int off = 32; off > 0; off >>= 1) {
      wl += __shfl_down(wl, off);
      wh += __shfl_down(wh, off);
    }
    if (d == 0) { cs_lo[b] = wl; cs_hi[b] = wh; }
  }
}

// ------- kernel 5: chunk-offset sums + materialize PreLo/SufHi + scalars ---
// De-spilled: cache the 64 weight*h PRODUCTS; exact-range T-loops (+unroll 4).
__global__ __launch_bounds__(256) void write_prefix(const float* __restrict__ h,
                                                    const int* __restrict__ perm,
                                                    const float* __restrict__ w_hi,
                                                    const float* __restrict__ w_lo,
                                                    const float* __restrict__ T_lo,
                                                    const float* __restrict__ T_hi,
                                                    const float* __restrict__ cs_lo,
                                                    const float* __restrict__ cs_hi,
                                                    float* __restrict__ PreLo,
                                                    float* __restrict__ SufHi,
                                                    float* __restrict__ prelo_s,
                                                    float* __restrict__ sufhi_s) {
  const int d = threadIdx.x, b = blockIdx.x;
  const int j0 = b * CLEN;
  // wave 0 additionally computes the scalar denominator prefixes
  if (d < 64) {
    float accp = 0.f, acct = 0.f;
    for (int p = d; p < NCHUNK; p += 64) {
      float cl = cs_lo[p], ch = cs_hi[p];
      accp += (p < b) ? cl : 0.f;
      acct += (p > b) ? ch : 0.f;
    }
#pragma unroll
    for (int off = 32; off > 0; off >>= 1) {
      accp += __shfl_down(accp, off);
      acct += __shfl_down(acct, off);
    }
    float pres  = __shfl(accp, 0);
    float tails = __shfl(acct, 0);
    float wl = (d < 32) ? w_lo[j0 + d] : 0.f;
    float wh = (d < 32) ? w_hi[j0 + d] : 0.f;
    float pl = wl, ph = wh;  // inclusive prefix over 32 lanes
#pragma unroll
    for (int off = 1; off < 32; off <<= 1) {
      float a = __shfl_up(pl, off);
      float c = __shfl_up(ph, off);
      if (d >= off) { pl += a; ph += c; }
    }
    float chunk_hi_tot = __shfl(ph, 31);
    if (d < 32) {
      prelo_s[j0 + d] = pres + (pl - wl);
      sufhi_s[j0 + d] = tails + (chunk_hi_tot - (ph - wh));
    }
    if (b == NCHUNK - 1 && d == 31) {
      prelo_s[NROW] = pres + pl;
      sufhi_s[NROW] = 0.f;
    }
  }
  float rl = 0.f, tail = 0.f;
#pragma unroll 4
  for (int p = 0; p < b; ++p)           rl   += T_lo[p * DOUT + d];
#pragma unroll 4
  for (int p = b + 1; p < NCHUNK; ++p)  tail += T_hi[p * DOUT + d];
  float phl[CLEN], phh[CLEN];
  float ownHi = 0.f;
#pragma unroll
  for (int e = 0; e < CLEN; e += 4) {
    int4 p4 = *(const int4*)(perm + j0 + e);
    float4 wl4 = *(const float4*)(w_lo + j0 + e);
    float4 wh4 = *(const float4*)(w_hi + j0 + e);
    float h0 = h[(size_t)p4.x * DOUT + d];
    float h1 = h[(size_t)p4.y * DOUT + d];
    float h2 = h[(size_t)p4.z * DOUT + d];
    float h3 = h[(size_t)p4.w * DOUT + d];
    phl[e + 0] = wl4.x * h0; phl[e + 1] = wl4.y * h1;
    phl[e + 2] = wl4.z * h2; phl[e + 3] = wl4.w * h3;
    phh[e + 0] = wh4.x * h0; phh[e + 1] = wh4.y * h1;
    phh[e + 2] = wh4.z * h2; phh[e + 3] = wh4.w * h3;
    ownHi += phh[e + 0] + phh[e + 1] + phh[e + 2] + phh[e + 3];
  }
  float shb = tail + ownHi;
  float preh = 0.f;
#pragma unroll
  for (int e = 0; e < CLEN; ++e) {
    size_t j = (size_t)(j0 + e);
    PreLo[j * DOUT + d] = rl;
    SufHi[j * DOUT + d] = shb - preh;
    rl   += phl[e];
    preh += phh[e];
  }
  if (b == NCHUNK - 1) {
    PreLo[(size_t)NROW * DOUT + d] = rl;
    SufHi[(size_t)NROW * DOUT + d] = 0.f;
  }
}

// ---------------- kernel 6: per-row combine -------------------------------
__global__ __launch_bounds__(256) void finalize(const float* __restrict__ s2,
                                                const float* __restrict__ s1s,
                                                const float* __restrict__ miscf,
                                                const float* __restrict__ PreLo,
                                                const float* __restrict__ SufHi,
                                                const float* __restrict__ prelo_s,
                                                const float* __restrict__ sufhi_s,
                                                float* __restrict__ out) {
  const int wave = threadIdx.x >> 6, lane = threadIdx.x & 63;
  const int i = blockIdx.x * 4 + wave;
  const float c = s2[i];
  const float M1 = miscf[0];
  const float tval = -c;
  int lo = 0, hi = NROW;
  while (lo < hi) {
    int mid = (lo + hi) >> 1;
    if (s1s[mid] <= tval) lo = mid + 1; else hi = mid;
  }
  const int k = lo;
  const float u = c + M1;
  const float m = fmaxf(u, 0.2f * u);
  const float fh = __expf(u - m);
  const float fl = __expf(0.2f * u - m);
  const float den = fh * sufhi_s[k] + fl * prelo_s[k];
  const float inv = 1.f / den;
  float4 A = *(const float4*)(SufHi + (size_t)k * DOUT + (lane << 2));
  float4 B = *(const float4*)(PreLo + (size_t)k * DOUT + (lane << 2));
  float4 o;
  o.x = (fh * A.x + fl * B.x) * inv;
  o.y = (fh * A.y + fl * B.y) * inv;
  o.z = (fh * A.z + fl * B.z) * inv;
  o.w = (fh * A.w + fl * B.w) * inv;
  *(float4*)(out + (size_t)i * DOUT + (lane << 2)) = o;
}

extern "C" void kernel_launch(void* const* d_in, const int* in_sizes, int n_in,
                              void* d_out, int out_size, void* d_ws, size_t ws_size,
                              hipStream_t stream) {
  const float* x  = (const float*)d_in[0];
  const float* W  = (const float*)d_in[2];
  const float* a1 = (const float*)d_in[3];
  const float* a2 = (const float*)d_in[4];
  float* out = (float*)d_out;

  char* ws = (char*)d_ws;
  if (ws_size < WS_NEED) ws = (char*)d_in[1];  // fall back to unused adj buffer

  float*          h       = (float*)(ws + OFF_H);
  float*          s1      = (float*)(ws + OFF_S1);
  float*          s2      = (float*)(ws + OFF_S2);
  int*            rank    = (int*)  (ws + OFF_RANK);
  unsigned int*   miscu   = (unsigned int*)(ws + OFF_MISC);
  float*          miscf   = (float*)(ws + OFF_MISC) + 1;
  float*          s1s     = (float*)(ws + OFF_S1S);
  int*            perm    = (int*)  (ws + OFF_PERM);
  float*          w_hi    = (float*)(ws + OFF_WHI);
  float*          w_lo    = (float*)(ws + OFF_WLO);
  float*          prelo_s = (float*)(ws + OFF_PRELOS);
  float*          sufhi_s = (float*)(ws + OFF_SUFHIS);
  float*          cs_lo   = (float*)(ws + OFF_CSLO);
  float*          cs_hi   = (float*)(ws + OFF_CSHI);
  float*          T_lo    = (float*)(ws + OFF_TLO);
  float*          T_hi    = (float*)(ws + OFF_THI);
  float*          PreLo   = (float*)(ws + OFF_PRELO);
  float*          SufHi   = (float*)(ws + OFF_SUFHI);
  unsigned short* Xhi     = (unsigned short*)(ws + OFF_XHI);
  unsigned short* Xlo     = (unsigned short*)(ws + OFF_XLO);
  unsigned short* Bhi     = (unsigned short*)(ws + OFF_BHI);
  unsigned short* Blo     = (unsigned short*)(ws + OFF_BLO);

  // zero s1,s2,rank,misc (contiguous) for the atomic accumulations
  hipMemsetAsync(s1, 0, MEMSET_LEN, stream);

  split_inputs<<<2048 + 64, 256, 0, stream>>>(x, W, Xhi, Xlo, Bhi, Blo);
  gemm_h_mfma<<<512, 256, 0, stream>>>(Xhi, Xlo, Bhi, Blo, a1, a2, h, s1, s2);
  rank_count<<<dim3(NROW / 256, 8), 256, 0, stream>>>(s1, rank, miscu);
  scatter_w<<<NROW / 256, 256, 0, stream>>>(s1, rank, miscu, miscf, s1s, perm, w_hi, w_lo);
  chunk_totals<<<NCHUNK, 256, 0, stream>>>(h, perm, w_hi, w_lo, T_lo, T_hi, cs_lo, cs_hi);
  write_prefix<<<NCHUNK, 256, 0, stream>>>(h, perm, w_hi, w_lo, T_lo, T_hi, cs_lo, cs_hi,
                                           PreLo, SufHi, prelo_s, sufhi_s);
  finalize<<<NROW / 4, 256, 0, stream>>>(s2, s1s, miscf, PreLo, SufHi, prelo_s, sufhi_s, out);
}

// Round 5
// 384.743 us; speedup vs baseline: 1.1240x; 1.0083x over previous
//
#include <hip/hip_runtime.h>

#define NROW 8192
#define DIN  512
#define DOUT 256
#define NCHUNK 256
#define CLEN 32   // NCHUNK*CLEN == NROW

// ---------------- workspace layout (bytes) ----------------
constexpr size_t OFF_H      = 0;                              // 8192*256*4
constexpr size_t OFF_S1     = OFF_H + (size_t)NROW*DOUT*4;    // ---- memset region start
constexpr size_t OFF_S2     = OFF_S1 + NROW*4;
constexpr size_t OFF_RANK   = OFF_S2 + NROW*4;
constexpr size_t OFF_MISC   = OFF_RANK + NROW*4;              // [0]=enc-max u32, [1]=M1 float
constexpr size_t MEMSET_LEN = OFF_MISC + 256 - OFF_S1;        // s1,s2,rank,misc contiguous
constexpr size_t OFF_S1S    = OFF_MISC + 256;
constexpr size_t OFF_PERM   = OFF_S1S + NROW*4;
constexpr size_t OFF_WHI    = OFF_PERM + NROW*4;
constexpr size_t OFF_WLO    = OFF_WHI + NROW*4;
constexpr size_t OFF_PRELOS = OFF_WLO + NROW*4;               // 8193 floats, padded
constexpr size_t OFF_SUFHIS = OFF_PRELOS + 33024;
constexpr size_t OFF_CSLO   = OFF_SUFHIS + 33024;             // [NCHUNK] scalar chunk sums
constexpr size_t OFF_CSHI   = OFF_CSLO + 1024;
constexpr size_t OFF_TLO    = OFF_CSHI + 1024;                // [NCHUNK][256]
constexpr size_t OFF_THI    = OFF_TLO + (size_t)NCHUNK*DOUT*4;
constexpr size_t OFF_PRELO  = OFF_THI + (size_t)NCHUNK*DOUT*4;  // [8193][256]
constexpr size_t OFF_SUFHI  = OFF_PRELO + (size_t)(NROW+1)*DOUT*4;
constexpr size_t WS_NEED    = OFF_SUFHI + (size_t)(NROW+1)*DOUT*4;

typedef float f32x4 __attribute__((ext_vector_type(4)));
typedef short s16x8 __attribute__((ext_vector_type(8)));

__device__ __forceinline__ unsigned short bf16_rne(float f) {
  unsigned int u = __float_as_uint(f);
  return (unsigned short)((u + 0x7fffu + ((u >> 16) & 1u)) >> 16);
}

// fp32 x8 -> bf16 hi/lo split (RNE both parts) — same math as the old
// split_inputs kernel, now done in-register inside the GEMM.
__device__ __forceinline__ void cvt8_pair(const float4 u, const float4 v,
                                          s16x8& hi, s16x8& lo) {
  float f[8] = {u.x, u.y, u.z, u.w, v.x, v.y, v.z, v.w};
#pragma unroll
  for (int j = 0; j < 8; ++j) {
    unsigned short hh = bf16_rne(f[j]);
    float r = f[j] - __uint_as_float(((unsigned int)hh) << 16);
    hi[j] = (short)hh;
    lo[j] = (short)bf16_rne(r);
  }
}

// ------- kernel 1: h = x @ W^T via split-bf16 MFMA, fused s1/s2 ------------
// Round-2 structure (64x64 tile, 512 blocks = 2/CU grid-limited occupancy,
// XCD-chunked swizzle) with two changes:
//  (1) fp32->bf16 hi/lo conversion IN-KERNEL (split_inputs kernel removed;
//      saves ~34 MB HBM of intermediate traffic + a launch). Conversion VALU
//      runs in the MFMA phase, not between barriers.
//  (2) BK=64: 8 K-steps instead of 16 -> 16 barrier drains instead of 32.
//      LDS 36.9 KB; occupancy still 2 blocks/CU (grid-limited, unlike the
//      round-3 1-block/CU regression).
// Pitch 72 bf16 (144 B): same balanced-bank residue class as verified
// pitch-40 (8 lanes per 4-bank group on b128 reads and writes).
__global__ __launch_bounds__(256) void gemm_h_mfma(const float* __restrict__ x,
                                                   const float* __restrict__ W,
                                                   const float* __restrict__ a1,
                                                   const float* __restrict__ a2,
                                                   float* __restrict__ h,
                                                   float* __restrict__ s1,
                                                   float* __restrict__ s2) {
  __shared__ unsigned short AsH[64][72], AsL[64][72], BsH[64][72], BsL[64][72];
  const int tid = threadIdx.x;
  // bijective XCD swizzle: nwg=512, 8 XCDs, 64 blocks/XCD-chunk
  const int bid = blockIdx.x;
  const int swz = (bid & 7) * 64 + (bid >> 3);
  const int rowBase = (swz >> 2) * 64;   // 128 row tiles
  const int colBase = (swz & 3) * 64;    // 4 col tiles (same A-panel adjacent)
  const int wid = tid >> 6, lane = tid & 63;
  const int wRow = wid >> 1, wCol = wid & 1;      // 2x2 wave grid
  const int lhi = lane >> 4, llo = lane & 15;

  f32x4 acc[2][2];
#pragma unroll
  for (int m = 0; m < 2; ++m)
#pragma unroll
    for (int n = 0; n < 2; ++n) acc[m][n] = (f32x4)(0.f);

  // staging: thread (tr, tq) owns row tr, k-range [tq*16, tq*16+16) of the
  // 64x64 fp32 tiles of both A (x) and B (W).
  const int tr = tid >> 2;   // 0..63
  const int tq = tid & 3;    // 0..3
  const float* px = x + (size_t)(rowBase + tr) * DIN + tq * 16;
  const float* pw = W + (size_t)(colBase + tr) * DIN + tq * 16;

  s16x8 cAh[2], cAl[2], cBh[2], cBl[2];
  {
    float4 a0 = *(const float4*)(px + 0),  a1v = *(const float4*)(px + 4);
    float4 a2v = *(const float4*)(px + 8), a3 = *(const float4*)(px + 12);
    float4 b0 = *(const float4*)(pw + 0),  b1 = *(const float4*)(pw + 4);
    float4 b2 = *(const float4*)(pw + 8),  b3 = *(const float4*)(pw + 12);
    cvt8_pair(a0, a1v, cAh[0], cAl[0]);
    cvt8_pair(a2v, a3, cAh[1], cAl[1]);
    cvt8_pair(b0, b1, cBh[0], cBl[0]);
    cvt8_pair(b2, b3, cBh[1], cBl[1]);
  }

  for (int k0 = 0; k0 < DIN; k0 += 64) {
    __syncthreads();  // previous step's frag reads complete
    *(s16x8*)&AsH[tr][tq * 16 + 0] = cAh[0];
    *(s16x8*)&AsH[tr][tq * 16 + 8] = cAh[1];
    *(s16x8*)&AsL[tr][tq * 16 + 0] = cAl[0];
    *(s16x8*)&AsL[tr][tq * 16 + 8] = cAl[1];
    *(s16x8*)&BsH[tr][tq * 16 + 0] = cBh[0];
    *(s16x8*)&BsH[tr][tq * 16 + 8] = cBh[1];
    *(s16x8*)&BsL[tr][tq * 16 + 0] = cBl[0];
    *(s16x8*)&BsL[tr][tq * 16 + 8] = cBl[1];
    __syncthreads();  // staged tile visible
    const bool more = (k0 + 64 < DIN);
    float4 a0, a1v, a2v, a3, b0, b1, b2, b3;
    if (more) {  // prefetch next step's fp32 (consumed by cvt after MFMAs)
      a0 = *(const float4*)(px + k0 + 64 + 0);  a1v = *(const float4*)(px + k0 + 64 + 4);
      a2v = *(const float4*)(px + k0 + 64 + 8); a3 = *(const float4*)(px + k0 + 64 + 12);
      b0 = *(const float4*)(pw + k0 + 64 + 0);  b1 = *(const float4*)(pw + k0 + 64 + 4);
      b2 = *(const float4*)(pw + k0 + 64 + 8);  b3 = *(const float4*)(pw + k0 + 64 + 12);
    }
#pragma unroll
    for (int kk = 0; kk < 64; kk += 32) {
      s16x8 afh[2], afl[2], bfh[2], bfl[2];
#pragma unroll
      for (int m = 0; m < 2; ++m) {
        afh[m] = *(const s16x8*)&AsH[wRow * 32 + m * 16 + llo][kk + lhi * 8];
        afl[m] = *(const s16x8*)&AsL[wRow * 32 + m * 16 + llo][kk + lhi * 8];
      }
#pragma unroll
      for (int n = 0; n < 2; ++n) {
        bfh[n] = *(const s16x8*)&BsH[wCol * 32 + n * 16 + llo][kk + lhi * 8];
        bfl[n] = *(const s16x8*)&BsL[wCol * 32 + n * 16 + llo][kk + lhi * 8];
      }
#pragma unroll
      for (int m = 0; m < 2; ++m)
#pragma unroll
        for (int n = 0; n < 2; ++n) {
          acc[m][n] = __builtin_amdgcn_mfma_f32_16x16x32_bf16(afh[m], bfh[n], acc[m][n], 0, 0, 0);
          acc[m][n] = __builtin_amdgcn_mfma_f32_16x16x32_bf16(afl[m], bfh[n], acc[m][n], 0, 0, 0);
          acc[m][n] = __builtin_amdgcn_mfma_f32_16x16x32_bf16(afh[m], bfl[n], acc[m][n], 0, 0, 0);
        }
    }
    if (more) {  // convert during/after MFMA phase (not between barriers)
      cvt8_pair(a0, a1v, cAh[0], cAl[0]);
      cvt8_pair(a2v, a3, cAh[1], cAl[1]);
      cvt8_pair(b0, b1, cBh[0], cBl[0]);
      cvt8_pair(b2, b3, cBh[1], cBl[1]);
    }
  }
  // C/D layout (m89-verified): col = lane&15, row = (lane>>4)*4 + reg
  float a1c[2], a2c[2];
#pragma unroll
  for (int n = 0; n < 2; ++n) {
    const int col = colBase + wCol * 32 + n * 16 + llo;
    a1c[n] = a1[col];
    a2c[n] = a2[col];
  }
#pragma unroll
  for (int m = 0; m < 2; ++m) {
    float p1[4] = {0.f, 0.f, 0.f, 0.f}, p2[4] = {0.f, 0.f, 0.f, 0.f};
#pragma unroll
    for (int n = 0; n < 2; ++n) {
      const int col = colBase + wCol * 32 + n * 16 + llo;
#pragma unroll
      for (int j = 0; j < 4; ++j) {
        const int row = rowBase + wRow * 32 + m * 16 + lhi * 4 + j;
        h[(size_t)row * DOUT + col] = acc[m][n][j];
        p1[j] = fmaf(acc[m][n][j], a1c[n], p1[j]);
        p2[j] = fmaf(acc[m][n][j], a2c[n], p2[j]);
      }
    }
#pragma unroll
    for (int j = 0; j < 4; ++j) {
#pragma unroll
      for (int msk = 1; msk < 16; msk <<= 1) {
        p1[j] += __shfl_xor(p1[j], msk);
        p2[j] += __shfl_xor(p2[j], msk);
      }
    }
    if (llo == 0) {
#pragma unroll
      for (int j = 0; j < 4; ++j) {
        const int row = rowBase + wRow * 32 + m * 16 + lhi * 4 + j;
        atomicAdd(&s1[row], p1[j]);
        atomicAdd(&s2[row], p2[j]);
      }
    }
  }
}

// ------- kernel 2: rank by counting (atomicAdd into rank) + global max -----
__global__ __launch_bounds__(256) void rank_count(const float* __restrict__ s1,
                                                  int* __restrict__ rank,
                                                  unsigned int* __restrict__ miscu) {
  __shared__ float sj[1024];
  __shared__ float wm[4];
  const int t = threadIdx.x;
  const int ib = blockIdx.x, jc = blockIdx.y;
  const int j0 = jc * 1024;
  *(float4*)&sj[t << 2] = *(const float4*)(s1 + j0 + (t << 2));
  const int i = ib * 256 + t;
  const float v = s1[i];
  __syncthreads();
  int cnt = 0;
#pragma unroll 4
  for (int q = 0; q < 256; ++q) {
    float4 sv = *(const float4*)&sj[q << 2];
    int jg = j0 + (q << 2);
    cnt += (int)(sv.x < v) + (int)((sv.x == v) & (jg + 0 < i));
    cnt += (int)(sv.y < v) + (int)((sv.y == v) & (jg + 1 < i));
    cnt += (int)(sv.z < v) + (int)((sv.z == v) & (jg + 2 < i));
    cnt += (int)(sv.w < v) + (int)((sv.w == v) & (jg + 3 < i));
  }
  atomicAdd(&rank[i], cnt);
  if (jc == 0) {  // one layer computes global max of s1 (monotone-uint atomicMax)
    float m = v;
#pragma unroll
    for (int off = 32; off > 0; off >>= 1) m = fmaxf(m, __shfl_down(m, off));
    if ((t & 63) == 0) wm[t >> 6] = m;
    __syncthreads();
    if (t == 0) {
      float mm = fmaxf(fmaxf(wm[0], wm[1]), fmaxf(wm[2], wm[3]));
      unsigned int b = __float_as_uint(mm);
      unsigned int enc = (b & 0x80000000u) ? ~b : (b | 0x80000000u);
      atomicMax(miscu, enc);
    }
  }
}

// ------- kernel 3: scatter into sorted order + exp weights -----------------
__global__ __launch_bounds__(256) void scatter_w(const float* __restrict__ s1,
                                                 const int* __restrict__ rank,
                                                 const unsigned int* __restrict__ miscu,
                                                 float* __restrict__ miscf,
                                                 float* __restrict__ s1s,
                                                 int* __restrict__ perm,
                                                 float* __restrict__ w_hi,
                                                 float* __restrict__ w_lo) {
  const int i = blockIdx.x * 256 + threadIdx.x;
  unsigned int e = miscu[0];
  unsigned int b = (e & 0x80000000u) ? (e & 0x7fffffffu) : ~e;
  const float M1 = __uint_as_float(b);
  const float v = s1[i];
  const int r = rank[i];
  s1s[r] = v;
  perm[r] = i;
  w_hi[r] = __expf(v - M1);
  w_lo[r] = __expf(0.2f * (v - M1));
  if (i == 0) miscf[0] = M1;
}

// ------- kernel 4: per-chunk weighted totals + scalar chunk sums -----------
__global__ __launch_bounds__(256) void chunk_totals(const float* __restrict__ h,
                                                    const int* __restrict__ perm,
                                                    const float* __restrict__ w_hi,
                                                    const float* __restrict__ w_lo,
                                                    float* __restrict__ T_lo,
                                                    float* __restrict__ T_hi,
                                                    float* __restrict__ cs_lo,
                                                    float* __restrict__ cs_hi) {
  const int d = threadIdx.x, b = blockIdx.x;
  const int j0 = b * CLEN;
  float tlo = 0.f, thi = 0.f;
#pragma unroll
  for (int e = 0; e < CLEN; e += 4) {
    int4 p4 = *(const int4*)(perm + j0 + e);
    float4 wl4 = *(const float4*)(w_lo + j0 + e);
    float4 wh4 = *(const float4*)(w_hi + j0 + e);
    float h0 = h[(size_t)p4.x * DOUT + d];
    float h1 = h[(size_t)p4.y * DOUT + d];
    float h2 = h[(size_t)p4.z * DOUT + d];
    float h3 = h[(size_t)p4.w * DOUT + d];
    tlo += wl4.x * h0 + wl4.y * h1 + wl4.z * h2 + wl4.w * h3;
    thi += wh4.x * h0 + wh4.y * h1 + wh4.z * h2 + wh4.w * h3;
  }
  T_lo[b * DOUT + d] = tlo;
  T_hi[b * DOUT + d] = thi;
  if (d < 64) {  // wave 0: scalar sums of this chunk's weights
    float wl = (d < 32) ? w_lo[j0 + d] : 0.f;
    float wh = (d < 32) ? w_hi[j0 + d] : 0.f;
#pragma unroll
    for (int off = 32; off > 0; off >>= 1) {
      wl += __shfl_down(wl, off);
      wh += __shfl_down(wh, off);
    }
    if (d == 0) { cs_lo[b] = wl; cs_hi[b] = wh; }
  }
}

// ------- kernel 5: chunk-offset sums + materialize PreLo/SufHi + scalars ---
__global__ __launch_bounds__(256) void write_prefix(const float* __restrict__ h,
                                                    const int* __restrict__ perm,
                                                    const float* __restrict__ w_hi,
                                                    const float* __restrict__ w_lo,
                                                    const float* __restrict__ T_lo,
                                                    const float* __restrict__ T_hi,
                                                    const float* __restrict__ cs_lo,
                                                    const float* __restrict__ cs_hi,
                                                    float* __restrict__ PreLo,
                                                    float* __restrict__ SufHi,
                                                    float* __restrict__ prelo_s,
                                                    float* __restrict__ sufhi_s) {
  const int d = threadIdx.x, b = blockIdx.x;
  const int j0 = b * CLEN;
  // wave 0 additionally computes the scalar denominator prefixes
  if (d < 64) {
    float accp = 0.f, acct = 0.f;
    for (int p = d; p < NCHUNK; p += 64) {
      float cl = cs_lo[p], ch = cs_hi[p];
      accp += (p < b) ? cl : 0.f;
      acct += (p > b) ? ch : 0.f;
    }
#pragma unroll
    for (int off = 32; off > 0; off >>= 1) {
      accp += __shfl_down(accp, off);
      acct += __shfl_down(acct, off);
    }
    float pres  = __shfl(accp, 0);
    float tails = __shfl(acct, 0);
    float wl = (d < 32) ? w_lo[j0 + d] : 0.f;
    float wh = (d < 32) ? w_hi[j0 + d] : 0.f;
    float pl = wl, ph = wh;  // inclusive prefix over 32 lanes
#pragma unroll
    for (int off = 1; off < 32; off <<= 1) {
      float a = __shfl_up(pl, off);
      float c = __shfl_up(ph, off);
      if (d >= off) { pl += a; ph += c; }
    }
    float chunk_hi_tot = __shfl(ph, 31);
    if (d < 32) {
      prelo_s[j0 + d] = pres + (pl - wl);
      sufhi_s[j0 + d] = tails + (chunk_hi_tot - (ph - wh));
    }
    if (b == NCHUNK - 1 && d == 31) {
      prelo_s[NROW] = pres + pl;
      sufhi_s[NROW] = 0.f;
    }
  }
  float rl = 0.f, tail = 0.f;
#pragma unroll 4
  for (int p = 0; p < b; ++p)           rl   += T_lo[p * DOUT + d];
#pragma unroll 4
  for (int p = b + 1; p < NCHUNK; ++p)  tail += T_hi[p * DOUT + d];
  float phl[CLEN], phh[CLEN];
  float ownHi = 0.f;
#pragma unroll
  for (int e = 0; e < CLEN; e += 4) {
    int4 p4 = *(const int4*)(perm + j0 + e);
    float4 wl4 = *(const float4*)(w_lo + j0 + e);
    float4 wh4 = *(const float4*)(w_hi + j0 + e);
    float h0 = h[(size_t)p4.x * DOUT + d];
    float h1 = h[(size_t)p4.y * DOUT + d];
    float h2 = h[(size_t)p4.z * DOUT + d];
    float h3 = h[(size_t)p4.w * DOUT + d];
    phl[e + 0] = wl4.x * h0; phl[e + 1] = wl4.y * h1;
    phl[e + 2] = wl4.z * h2; phl[e + 3] = wl4.w * h3;
    phh[e + 0] = wh4.x * h0; phh[e + 1] = wh4.y * h1;
    phh[e + 2] = wh4.z * h2; phh[e + 3] = wh4.w * h3;
    ownHi += phh[e + 0] + phh[e + 1] + phh[e + 2] + phh[e + 3];
  }
  float shb = tail + ownHi;
  float preh = 0.f;
#pragma unroll
  for (int e = 0; e < CLEN; ++e) {
    size_t j = (size_t)(j0 + e);
    PreLo[j * DOUT + d] = rl;
    SufHi[j * DOUT + d] = shb - preh;
    rl   += phl[e];
    preh += phh[e];
  }
  if (b == NCHUNK - 1) {
    PreLo[(size_t)NROW * DOUT + d] = rl;
    SufHi[(size_t)NROW * DOUT + d] = 0.f;
  }
}

// ---------------- kernel 6: per-row combine -------------------------------
__global__ __launch_bounds__(256) void finalize(const float* __restrict__ s2,
                                                const float* __restrict__ s1s,
                                                const float* __restrict__ miscf,
                                                const float* __restrict__ PreLo,
                                                const float* __restrict__ SufHi,
                                                const float* __restrict__ prelo_s,
                                                const float* __restrict__ sufhi_s,
                                                float* __restrict__ out) {
  const int wave = threadIdx.x >> 6, lane = threadIdx.x & 63;
  const int i = blockIdx.x * 4 + wave;
  const float c = s2[i];
  const float M1 = miscf[0];
  const float tval = -c;
  int lo = 0, hi = NROW;
  while (lo < hi) {
    int mid = (lo + hi) >> 1;
    if (s1s[mid] <= tval) lo = mid + 1; else hi = mid;
  }
  const int k = lo;
  const float u = c + M1;
  const float m = fmaxf(u, 0.2f * u);
  const float fh = __expf(u - m);
  const float fl = __expf(0.2f * u - m);
  const float den = fh * sufhi_s[k] + fl * prelo_s[k];
  const float inv = 1.f / den;
  float4 A = *(const float4*)(SufHi + (size_t)k * DOUT + (lane << 2));
  float4 B = *(const float4*)(PreLo + (size_t)k * DOUT + (lane << 2));
  float4 o;
  o.x = (fh * A.x + fl * B.x) * inv;
  o.y = (fh * A.y + fl * B.y) * inv;
  o.z = (fh * A.z + fl * B.z) * inv;
  o.w = (fh * A.w + fl * B.w) * inv;
  *(float4*)(out + (size_t)i * DOUT + (lane << 2)) = o;
}

extern "C" void kernel_launch(void* const* d_in, const int* in_sizes, int n_in,
                              void* d_out, int out_size, void* d_ws, size_t ws_size,
                              hipStream_t stream) {
  const float* x  = (const float*)d_in[0];
  const float* W  = (const float*)d_in[2];
  const float* a1 = (const float*)d_in[3];
  const float* a2 = (const float*)d_in[4];
  float* out = (float*)d_out;

  char* ws = (char*)d_ws;
  if (ws_size < WS_NEED) ws = (char*)d_in[1];  // fall back to unused adj buffer

  float*          h       = (float*)(ws + OFF_H);
  float*          s1      = (float*)(ws + OFF_S1);
  float*          s2      = (float*)(ws + OFF_S2);
  int*            rank    = (int*)  (ws + OFF_RANK);
  unsigned int*   miscu   = (unsigned int*)(ws + OFF_MISC);
  float*          miscf   = (float*)(ws + OFF_MISC) + 1;
  float*          s1s     = (float*)(ws + OFF_S1S);
  int*            perm    = (int*)  (ws + OFF_PERM);
  float*          w_hi    = (float*)(ws + OFF_WHI);
  float*          w_lo    = (float*)(ws + OFF_WLO);
  float*          prelo_s = (float*)(ws + OFF_PRELOS);
  float*          sufhi_s = (float*)(ws + OFF_SUFHIS);
  float*          cs_lo   = (float*)(ws + OFF_CSLO);
  float*          cs_hi   = (float*)(ws + OFF_CSHI);
  float*          T_lo    = (float*)(ws + OFF_TLO);
  float*          T_hi    = (float*)(ws + OFF_THI);
  float*          PreLo   = (float*)(ws + OFF_PRELO);
  float*          SufHi   = (float*)(ws + OFF_SUFHI);

  // zero s1,s2,rank,misc (contiguous) for the atomic accumulations
  hipMemsetAsync(s1, 0, MEMSET_LEN, stream);

  gemm_h_mfma<<<512, 256, 0, stream>>>(x, W, a1, a2, h, s1, s2);
  rank_count<<<dim3(NROW / 256, 8), 256, 0, stream>>>(s1, rank, miscu);
  scatter_w<<<NROW / 256, 256, 0, stream>>>(s1, rank, miscu, miscf, s1s, perm, w_hi, w_lo);
  chunk_totals<<<NCHUNK, 256, 0, stream>>>(h, perm, w_hi, w_lo, T_lo, T_hi, cs_lo, cs_hi);
  write_prefix<<<NCHUNK, 256, 0, stream>>>(h, perm, w_hi, w_lo, T_lo, T_hi, cs_lo, cs_hi,
                                           PreLo, SufHi, prelo_s, sufhi_s);
  finalize<<<NROW / 4, 256, 0, stream>>>(s2, s1s, miscf, PreLo, SufHi, prelo_s, sufhi_s, out);
}

// Round 6
// 381.839 us; speedup vs baseline: 1.1325x; 1.0076x over previous
//
#include <hip/hip_runtime.h>

#define NROW 8192
#define DIN  512
#define DOUT 256
#define NCHUNK 256
#define CLEN 32   // NCHUNK*CLEN == NROW

// ---------------- workspace layout (bytes) ----------------
constexpr size_t OFF_H      = 0;                              // 8192*256*4
constexpr size_t OFF_S1     = OFF_H + (size_t)NROW*DOUT*4;    // ---- memset region start
constexpr size_t OFF_S2     = OFF_S1 + NROW*4;
constexpr size_t OFF_RANK   = OFF_S2 + NROW*4;
constexpr size_t OFF_MISC   = OFF_RANK + NROW*4;              // [0]=enc-max u32, [1]=M1 float
constexpr size_t MEMSET_LEN = OFF_MISC + 256 - OFF_S1;        // s1,s2,rank,misc contiguous
constexpr size_t OFF_S1S    = OFF_MISC + 256;
constexpr size_t OFF_PERM   = OFF_S1S + NROW*4;
constexpr size_t OFF_WHI    = OFF_PERM + NROW*4;
constexpr size_t OFF_WLO    = OFF_WHI + NROW*4;
constexpr size_t OFF_PRELOS = OFF_WLO + NROW*4;               // 8193 floats, padded
constexpr size_t OFF_SUFHIS = OFF_PRELOS + 33024;
constexpr size_t OFF_CSLO   = OFF_SUFHIS + 33024;             // [NCHUNK] scalar chunk sums
constexpr size_t OFF_CSHI   = OFF_CSLO + 1024;
constexpr size_t OFF_TLO    = OFF_CSHI + 1024;                // [NCHUNK][256]
constexpr size_t OFF_THI    = OFF_TLO + (size_t)NCHUNK*DOUT*4;
constexpr size_t OFF_PRELO  = OFF_THI + (size_t)NCHUNK*DOUT*4;  // [8193][256]
constexpr size_t OFF_SUFHI  = OFF_PRELO + (size_t)(NROW+1)*DOUT*4;
constexpr size_t WS_NEED    = OFF_SUFHI + (size_t)(NROW+1)*DOUT*4;

typedef float f32x4 __attribute__((ext_vector_type(4)));
typedef short s16x8 __attribute__((ext_vector_type(8)));
typedef unsigned int u32x4 __attribute__((ext_vector_type(4)));

// fp32 x8 -> bf16 hi/lo TRUNCATING split, 3 VALU ops/element:
//   hi = top16(f)            (residual <= 2^-8 |f|)
//   lo = top16(f - hi)       (final residual <= 2^-16 |f| ~ size of the
//                             already-dropped lo*lo cross term)
// v_perm_b32 packs two truncations per instruction. Error on h ~2e-5,
// two orders below the observed absmax floor (2^-10, which is constant
// across rounds incl. the pure-fp32 round 0 -> dominated elsewhere).
__device__ __forceinline__ void cvt8_pair(const float4 u, const float4 v,
                                          s16x8& hi, s16x8& lo) {
  float f[8] = {u.x, u.y, u.z, u.w, v.x, v.y, v.z, v.w};
  u32x4 hp, lp;
#pragma unroll
  for (int p = 0; p < 4; ++p) {
    const float f0 = f[2 * p], f1 = f[2 * p + 1];
    const unsigned b0 = __float_as_uint(f0);
    const unsigned b1 = __float_as_uint(f1);
    hp[p] = __builtin_amdgcn_perm(b1, b0, 0x07060302u);  // [f0.hi16, f1.hi16]
    const float r0 = f0 - __uint_as_float(b0 & 0xffff0000u);
    const float r1 = f1 - __uint_as_float(b1 & 0xffff0000u);
    lp[p] = __builtin_amdgcn_perm(__float_as_uint(r1), __float_as_uint(r0), 0x07060302u);
  }
  hi = __builtin_bit_cast(s16x8, hp);
  lo = __builtin_bit_cast(s16x8, lp);
}

// ------- kernel 1: h = x @ W^T via split-bf16 MFMA, fused s1/s2 ------------
// Structure as round 5 (64x64 tile, BK=64, 512 blocks = 2/CU, XCD swizzle,
// in-kernel fp32->bf16hi/lo conversion). ONLY change: conversion now uses
// the truncating perm-based split above (96 VALU/thread/K-step vs ~340 with
// integer-RNE) — round 5's GEMM was VALU-bound on conversion arithmetic.
__global__ __launch_bounds__(256) void gemm_h_mfma(const float* __restrict__ x,
                                                   const float* __restrict__ W,
                                                   const float* __restrict__ a1,
                                                   const float* __restrict__ a2,
                                                   float* __restrict__ h,
                                                   float* __restrict__ s1,
                                                   float* __restrict__ s2) {
  __shared__ unsigned short AsH[64][72], AsL[64][72], BsH[64][72], BsL[64][72];
  const int tid = threadIdx.x;
  // bijective XCD swizzle: nwg=512, 8 XCDs, 64 blocks/XCD-chunk
  const int bid = blockIdx.x;
  const int swz = (bid & 7) * 64 + (bid >> 3);
  const int rowBase = (swz >> 2) * 64;   // 128 row tiles
  const int colBase = (swz & 3) * 64;    // 4 col tiles (same A-panel adjacent)
  const int wid = tid >> 6, lane = tid & 63;
  const int wRow = wid >> 1, wCol = wid & 1;      // 2x2 wave grid
  const int lhi = lane >> 4, llo = lane & 15;

  f32x4 acc[2][2];
#pragma unroll
  for (int m = 0; m < 2; ++m)
#pragma unroll
    for (int n = 0; n < 2; ++n) acc[m][n] = (f32x4)(0.f);

  // staging: thread (tr, tq) owns row tr, k-range [tq*16, tq*16+16) of the
  // 64x64 fp32 tiles of both A (x) and B (W).
  const int tr = tid >> 2;   // 0..63
  const int tq = tid & 3;    // 0..3
  const float* px = x + (size_t)(rowBase + tr) * DIN + tq * 16;
  const float* pw = W + (size_t)(colBase + tr) * DIN + tq * 16;

  s16x8 cAh[2], cAl[2], cBh[2], cBl[2];
  {
    float4 a0 = *(const float4*)(px + 0),  a1v = *(const float4*)(px + 4);
    float4 a2v = *(const float4*)(px + 8), a3 = *(const float4*)(px + 12);
    float4 b0 = *(const float4*)(pw + 0),  b1 = *(const float4*)(pw + 4);
    float4 b2 = *(const float4*)(pw + 8),  b3 = *(const float4*)(pw + 12);
    cvt8_pair(a0, a1v, cAh[0], cAl[0]);
    cvt8_pair(a2v, a3, cAh[1], cAl[1]);
    cvt8_pair(b0, b1, cBh[0], cBl[0]);
    cvt8_pair(b2, b3, cBh[1], cBl[1]);
  }

  for (int k0 = 0; k0 < DIN; k0 += 64) {
    __syncthreads();  // previous step's frag reads complete
    *(s16x8*)&AsH[tr][tq * 16 + 0] = cAh[0];
    *(s16x8*)&AsH[tr][tq * 16 + 8] = cAh[1];
    *(s16x8*)&AsL[tr][tq * 16 + 0] = cAl[0];
    *(s16x8*)&AsL[tr][tq * 16 + 8] = cAl[1];
    *(s16x8*)&BsH[tr][tq * 16 + 0] = cBh[0];
    *(s16x8*)&BsH[tr][tq * 16 + 8] = cBh[1];
    *(s16x8*)&BsL[tr][tq * 16 + 0] = cBl[0];
    *(s16x8*)&BsL[tr][tq * 16 + 8] = cBl[1];
    __syncthreads();  // staged tile visible
    const bool more = (k0 + 64 < DIN);
    float4 a0, a1v, a2v, a3, b0, b1, b2, b3;
    if (more) {  // prefetch next step's fp32 (consumed by cvt after MFMAs)
      a0 = *(const float4*)(px + k0 + 64 + 0);  a1v = *(const float4*)(px + k0 + 64 + 4);
      a2v = *(const float4*)(px + k0 + 64 + 8); a3 = *(const float4*)(px + k0 + 64 + 12);
      b0 = *(const float4*)(pw + k0 + 64 + 0);  b1 = *(const float4*)(pw + k0 + 64 + 4);
      b2 = *(const float4*)(pw + k0 + 64 + 8);  b3 = *(const float4*)(pw + k0 + 64 + 12);
    }
#pragma unroll
    for (int kk = 0; kk < 64; kk += 32) {
      s16x8 afh[2], afl[2], bfh[2], bfl[2];
#pragma unroll
      for (int m = 0; m < 2; ++m) {
        afh[m] = *(const s16x8*)&AsH[wRow * 32 + m * 16 + llo][kk + lhi * 8];
        afl[m] = *(const s16x8*)&AsL[wRow * 32 + m * 16 + llo][kk + lhi * 8];
      }
#pragma unroll
      for (int n = 0; n < 2; ++n) {
        bfh[n] = *(const s16x8*)&BsH[wCol * 32 + n * 16 + llo][kk + lhi * 8];
        bfl[n] = *(const s16x8*)&BsL[wCol * 32 + n * 16 + llo][kk + lhi * 8];
      }
#pragma unroll
      for (int m = 0; m < 2; ++m)
#pragma unroll
        for (int n = 0; n < 2; ++n) {
          acc[m][n] = __builtin_amdgcn_mfma_f32_16x16x32_bf16(afh[m], bfh[n], acc[m][n], 0, 0, 0);
          acc[m][n] = __builtin_amdgcn_mfma_f32_16x16x32_bf16(afl[m], bfh[n], acc[m][n], 0, 0, 0);
          acc[m][n] = __builtin_amdgcn_mfma_f32_16x16x32_bf16(afh[m], bfl[n], acc[m][n], 0, 0, 0);
        }
    }
    if (more) {  // convert during/after MFMA phase (not between barriers)
      cvt8_pair(a0, a1v, cAh[0], cAl[0]);
      cvt8_pair(a2v, a3, cAh[1], cAl[1]);
      cvt8_pair(b0, b1, cBh[0], cBl[0]);
      cvt8_pair(b2, b3, cBh[1], cBl[1]);
    }
  }
  // C/D layout (m89-verified): col = lane&15, row = (lane>>4)*4 + reg
  float a1c[2], a2c[2];
#pragma unroll
  for (int n = 0; n < 2; ++n) {
    const int col = colBase + wCol * 32 + n * 16 + llo;
    a1c[n] = a1[col];
    a2c[n] = a2[col];
  }
#pragma unroll
  for (int m = 0; m < 2; ++m) {
    float p1[4] = {0.f, 0.f, 0.f, 0.f}, p2[4] = {0.f, 0.f, 0.f, 0.f};
#pragma unroll
    for (int n = 0; n < 2; ++n) {
      const int col = colBase + wCol * 32 + n * 16 + llo;
#pragma unroll
      for (int j = 0; j < 4; ++j) {
        const int row = rowBase + wRow * 32 + m * 16 + lhi * 4 + j;
        h[(size_t)row * DOUT + col] = acc[m][n][j];
        p1[j] = fmaf(acc[m][n][j], a1c[n], p1[j]);
        p2[j] = fmaf(acc[m][n][j], a2c[n], p2[j]);
      }
    }
#pragma unroll
    for (int j = 0; j < 4; ++j) {
#pragma unroll
      for (int msk = 1; msk < 16; msk <<= 1) {
        p1[j] += __shfl_xor(p1[j], msk);
        p2[j] += __shfl_xor(p2[j], msk);
      }
    }
    if (llo == 0) {
#pragma unroll
      for (int j = 0; j < 4; ++j) {
        const int row = rowBase + wRow * 32 + m * 16 + lhi * 4 + j;
        atomicAdd(&s1[row], p1[j]);
        atomicAdd(&s2[row], p2[j]);
      }
    }
  }
}

// ------- kernel 2: rank by counting (atomicAdd into rank) + global max -----
__global__ __launch_bounds__(256) void rank_count(const float* __restrict__ s1,
                                                  int* __restrict__ rank,
                                                  unsigned int* __restrict__ miscu) {
  __shared__ float sj[1024];
  __shared__ float wm[4];
  const int t = threadIdx.x;
  const int ib = blockIdx.x, jc = blockIdx.y;
  const int j0 = jc * 1024;
  *(float4*)&sj[t << 2] = *(const float4*)(s1 + j0 + (t << 2));
  const int i = ib * 256 + t;
  const float v = s1[i];
  __syncthreads();
  int cnt = 0;
#pragma unroll 4
  for (int q = 0; q < 256; ++q) {
    float4 sv = *(const float4*)&sj[q << 2];
    int jg = j0 + (q << 2);
    cnt += (int)(sv.x < v) + (int)((sv.x == v) & (jg + 0 < i));
    cnt += (int)(sv.y < v) + (int)((sv.y == v) & (jg + 1 < i));
    cnt += (int)(sv.z < v) + (int)((sv.z == v) & (jg + 2 < i));
    cnt += (int)(sv.w < v) + (int)((sv.w == v) & (jg + 3 < i));
  }
  atomicAdd(&rank[i], cnt);
  if (jc == 0) {  // one layer computes global max of s1 (monotone-uint atomicMax)
    float m = v;
#pragma unroll
    for (int off = 32; off > 0; off >>= 1) m = fmaxf(m, __shfl_down(m, off));
    if ((t & 63) == 0) wm[t >> 6] = m;
    __syncthreads();
    if (t == 0) {
      float mm = fmaxf(fmaxf(wm[0], wm[1]), fmaxf(wm[2], wm[3]));
      unsigned int b = __float_as_uint(mm);
      unsigned int enc = (b & 0x80000000u) ? ~b : (b | 0x80000000u);
      atomicMax(miscu, enc);
    }
  }
}

// ------- kernel 3: scatter into sorted order + exp weights -----------------
__global__ __launch_bounds__(256) void scatter_w(const float* __restrict__ s1,
                                                 const int* __restrict__ rank,
                                                 const unsigned int* __restrict__ miscu,
                                                 float* __restrict__ miscf,
                                                 float* __restrict__ s1s,
                                                 int* __restrict__ perm,
                                                 float* __restrict__ w_hi,
                                                 float* __restrict__ w_lo) {
  const int i = blockIdx.x * 256 + threadIdx.x;
  unsigned int e = miscu[0];
  unsigned int b = (e & 0x80000000u) ? (e & 0x7fffffffu) : ~e;
  const float M1 = __uint_as_float(b);
  const float v = s1[i];
  const int r = rank[i];
  s1s[r] = v;
  perm[r] = i;
  w_hi[r] = __expf(v - M1);
  w_lo[r] = __expf(0.2f * (v - M1));
  if (i == 0) miscf[0] = M1;
}

// ------- kernel 4: per-chunk weighted totals + scalar chunk sums -----------
__global__ __launch_bounds__(256) void chunk_totals(const float* __restrict__ h,
                                                    const int* __restrict__ perm,
                                                    const float* __restrict__ w_hi,
                                                    const float* __restrict__ w_lo,
                                                    float* __restrict__ T_lo,
                                                    float* __restrict__ T_hi,
                                                    float* __restrict__ cs_lo,
                                                    float* __restrict__ cs_hi) {
  const int d = threadIdx.x, b = blockIdx.x;
  const int j0 = b * CLEN;
  float tlo = 0.f, thi = 0.f;
#pragma unroll
  for (int e = 0; e < CLEN; e += 4) {
    int4 p4 = *(const int4*)(perm + j0 + e);
    float4 wl4 = *(const float4*)(w_lo + j0 + e);
    float4 wh4 = *(const float4*)(w_hi + j0 + e);
    float h0 = h[(size_t)p4.x * DOUT + d];
    float h1 = h[(size_t)p4.y * DOUT + d];
    float h2 = h[(size_t)p4.z * DOUT + d];
    float h3 = h[(size_t)p4.w * DOUT + d];
    tlo += wl4.x * h0 + wl4.y * h1 + wl4.z * h2 + wl4.w * h3;
    thi += wh4.x * h0 + wh4.y * h1 + wh4.z * h2 + wh4.w * h3;
  }
  T_lo[b * DOUT + d] = tlo;
  T_hi[b * DOUT + d] = thi;
  if (d < 64) {  // wave 0: scalar sums of this chunk's weights
    float wl = (d < 32) ? w_lo[j0 + d] : 0.f;
    float wh = (d < 32) ? w_hi[j0 + d] : 0.f;
#pragma unroll
    for (int off = 32; off > 0; off >>= 1) {
      wl += __shfl_down(wl, off);
      wh += __shfl_down(wh, off);
    }
    if (d == 0) { cs_lo[b] = wl; cs_hi[b] = wh; }
  }
}

// ------- kernel 5: chunk-offset sums + materialize PreLo/SufHi + scalars ---
__global__ __launch_bounds__(256) void write_prefix(const float* __restrict__ h,
                                                    const int* __restrict__ perm,
                                                    const float* __restrict__ w_hi,
                                                    const float* __restrict__ w_lo,
                                                    const float* __restrict__ T_lo,
                                                    const float* __restrict__ T_hi,
                                                    const float* __restrict__ cs_lo,
                                                    const float* __restrict__ cs_hi,
                                                    float* __restrict__ PreLo,
                                                    float* __restrict__ SufHi,
                                                    float* __restrict__ prelo_s,
                                                    float* __restrict__ sufhi_s) {
  const int d = threadIdx.x, b = blockIdx.x;
  const int j0 = b * CLEN;
  // wave 0 additionally computes the scalar denominator prefixes
  if (d < 64) {
    float accp = 0.f, acct = 0.f;
    for (int p = d; p < NCHUNK; p += 64) {
      float cl = cs_lo[p], ch = cs_hi[p];
      accp += (p < b) ? cl : 0.f;
      acct += (p > b) ? ch : 0.f;
    }
#pragma unroll
    for (int off = 32; off > 0; off >>= 1) {
      accp += __shfl_down(accp, off);
      acct += __shfl_down(acct, off);
    }
    float pres  = __shfl(accp, 0);
    float tails = __shfl(acct, 0);
    float wl = (d < 32) ? w_lo[j0 + d] : 0.f;
    float wh = (d < 32) ? w_hi[j0 + d] : 0.f;
    float pl = wl, ph = wh;  // inclusive prefix over 32 lanes
#pragma unroll
    for (int off = 1; off < 32; off <<= 1) {
      float a = __shfl_up(pl, off);
      float c = __shfl_up(ph, off);
      if (d >= off) { pl += a; ph += c; }
    }
    float chunk_hi_tot = __shfl(ph, 31);
    if (d < 32) {
      prelo_s[j0 + d] = pres + (pl - wl);
      sufhi_s[j0 + d] = tails + (chunk_hi_tot - (ph - wh));
    }
    if (b == NCHUNK - 1 && d == 31) {
      prelo_s[NROW] = pres + pl;
      sufhi_s[NROW] = 0.f;
    }
  }
  float rl = 0.f, tail = 0.f;
#pragma unroll 4
  for (int p = 0; p < b; ++p)           rl   += T_lo[p * DOUT + d];
#pragma unroll 4
  for (int p = b + 1; p < NCHUNK; ++p)  tail += T_hi[p * DOUT + d];
  float phl[CLEN], phh[CLEN];
  float ownHi = 0.f;
#pragma unroll
  for (int e = 0; e < CLEN; e += 4) {
    int4 p4 = *(const int4*)(perm + j0 + e);
    float4 wl4 = *(const float4*)(w_lo + j0 + e);
    float4 wh4 = *(const float4*)(w_hi + j0 + e);
    float h0 = h[(size_t)p4.x * DOUT + d];
    float h1 = h[(size_t)p4.y * DOUT + d];
    float h2 = h[(size_t)p4.z * DOUT + d];
    float h3 = h[(size_t)p4.w * DOUT + d];
    phl[e + 0] = wl4.x * h0; phl[e + 1] = wl4.y * h1;
    phl[e + 2] = wl4.z * h2; phl[e + 3] = wl4.w * h3;
    phh[e + 0] = wh4.x * h0; phh[e + 1] = wh4.y * h1;
    phh[e + 2] = wh4.z * h2; phh[e + 3] = wh4.w * h3;
    ownHi += phh[e + 0] + phh[e + 1] + phh[e + 2] + phh[e + 3];
  }
  float shb = tail + ownHi;
  float preh = 0.f;
#pragma unroll
  for (int e = 0; e < CLEN; ++e) {
    size_t j = (size_t)(j0 + e);
    PreLo[j * DOUT + d] = rl;
    SufHi[j * DOUT + d] = shb - preh;
    rl   += phl[e];
    preh += phh[e];
  }
  if (b == NCHUNK - 1) {
    PreLo[(size_t)NROW * DOUT + d] = rl;
    SufHi[(size_t)NROW * DOUT + d] = 0.f;
  }
}

// ---------------- kernel 6: per-row combine -------------------------------
__global__ __launch_bounds__(256) void finalize(const float* __restrict__ s2,
                                                const float* __restrict__ s1s,
                                                const float* __restrict__ miscf,
                                                const float* __restrict__ PreLo,
                                                const float* __restrict__ SufHi,
                                                const float* __restrict__ prelo_s,
                                                const float* __restrict__ sufhi_s,
                                                float* __restrict__ out) {
  const int wave = threadIdx.x >> 6, lane = threadIdx.x & 63;
  const int i = blockIdx.x * 4 + wave;
  const float c = s2[i];
  const float M1 = miscf[0];
  const float tval = -c;
  int lo = 0, hi = NROW;
  while (lo < hi) {
    int mid = (lo + hi) >> 1;
    if (s1s[mid] <= tval) lo = mid + 1; else hi = mid;
  }
  const int k = lo;
  const float u = c + M1;
  const float m = fmaxf(u, 0.2f * u);
  const float fh = __expf(u - m);
  const float fl = __expf(0.2f * u - m);
  const float den = fh * sufhi_s[k] + fl * prelo_s[k];
  const float inv = 1.f / den;
  float4 A = *(const float4*)(SufHi + (size_t)k * DOUT + (lane << 2));
  float4 B = *(const float4*)(PreLo + (size_t)k * DOUT + (lane << 2));
  float4 o;
  o.x = (fh * A.x + fl * B.x) * inv;
  o.y = (fh * A.y + fl * B.y) * inv;
  o.z = (fh * A.z + fl * B.z) * inv;
  o.w = (fh * A.w + fl * B.w) * inv;
  *(float4*)(out + (size_t)i * DOUT + (lane << 2)) = o;
}

extern "C" void kernel_launch(void* const* d_in, const int* in_sizes, int n_in,
                              void* d_out, int out_size, void* d_ws, size_t ws_size,
                              hipStream_t stream) {
  const float* x  = (const float*)d_in[0];
  const float* W  = (const float*)d_in[2];
  const float* a1 = (const float*)d_in[3];
  const float* a2 = (const float*)d_in[4];
  float* out = (float*)d_out;

  char* ws = (char*)d_ws;
  if (ws_size < WS_NEED) ws = (char*)d_in[1];  // fall back to unused adj buffer

  float*          h       = (float*)(ws + OFF_H);
  float*          s1      = (float*)(ws + OFF_S1);
  float*          s2      = (float*)(ws + OFF_S2);
  int*            rank    = (int*)  (ws + OFF_RANK);
  unsigned int*   miscu   = (unsigned int*)(ws + OFF_MISC);
  float*          miscf   = (float*)(ws + OFF_MISC) + 1;
  float*          s1s     = (float*)(ws + OFF_S1S);
  int*            perm    = (int*)  (ws + OFF_PERM);
  float*          w_hi    = (float*)(ws + OFF_WHI);
  float*          w_lo    = (float*)(ws + OFF_WLO);
  float*          prelo_s = (float*)(ws + OFF_PRELOS);
  float*          sufhi_s = (float*)(ws + OFF_SUFHIS);
  float*          cs_lo   = (float*)(ws + OFF_CSLO);
  float*          cs_hi   = (float*)(ws + OFF_CSHI);
  float*          T_lo    = (float*)(ws + OFF_TLO);
  float*          T_hi    = (float*)(ws + OFF_THI);
  float*          PreLo   = (float*)(ws + OFF_PRELO);
  float*          SufHi   = (float*)(ws + OFF_SUFHI);

  // zero s1,s2,rank,misc (contiguous) for the atomic accumulations
  hipMemsetAsync(s1, 0, MEMSET_LEN, stream);

  gemm_h_mfma<<<512, 256, 0, stream>>>(x, W, a1, a2, h, s1, s2);
  rank_count<<<dim3(NROW / 256, 8), 256, 0, stream>>>(s1, rank, miscu);
  scatter_w<<<NROW / 256, 256, 0, stream>>>(s1, rank, miscu, miscf, s1s, perm, w_hi, w_lo);
  chunk_totals<<<NCHUNK, 256, 0, stream>>>(h, perm, w_hi, w_lo, T_lo, T_hi, cs_lo, cs_hi);
  write_prefix<<<NCHUNK, 256, 0, stream>>>(h, perm, w_hi, w_lo, T_lo, T_hi, cs_lo, cs_hi,
                                           PreLo, SufHi, prelo_s, sufhi_s);
  finalize<<<NROW / 4, 256, 0, stream>>>(s2, s1s, miscf, PreLo, SufHi, prelo_s, sufhi_s, out);
}